// Round 7
// baseline (119.334 us; speedup 1.0000x reference)
//
#include <hip/hip_runtime.h>
#include <math.h>

#define IMG_H 768
#define IMG_W 768
#define BATCH 16
#define TPB 256                     // 4 waves; each wave = one output row, 256-px x-span
#define XSPAN 256
#define NBX (IMG_W / XSPAN)         // 3
#define NBY (IMG_H / 4)             // 192 (4 output rows per block)
#define NBLOCKS (NBX * NBY * BATCH) // 9216
#define NPIX ((size_t)BATCH * IMG_H * IMG_W)  // 9437184

struct Row6 { float v[6]; };        // x0-1 .. x0+4

// Load one image row segment: one float4 + shfl x-halo + 2-lane edge load.
__device__ __forceinline__ Row6 lrow(const float* __restrict__ img, int row, int x0, int lane) {
    Row6 r;
    if (row < 0 || row >= IMG_H) {            // wave-uniform branch
        #pragma unroll
        for (int i = 0; i < 6; ++i) r.v[i] = 0.f;
        return r;
    }
    const float* p = img + row * IMG_W + x0;
    float4 m = *(const float4*)p;             // 16B-aligned
    float ev = 0.f;
    bool e0  = (lane == 0)  & (x0 > 0);
    bool e63 = (lane == 63) & (x0 + 4 < IMG_W);
    if (e0 | e63) ev = p[e0 ? -1 : 4];        // one VMEM, 2 active lanes/wave
    float left  = __shfl_up(m.w, 1);
    float right = __shfl_down(m.x, 1);
    if (lane == 0)  left  = ev;
    if (lane == 63) right = ev;
    r.v[0] = left; r.v[1] = m.x; r.v[2] = m.y; r.v[3] = m.z; r.v[4] = m.w; r.v[5] = right;
    return r;
}

__device__ __forceinline__ float sob(const Row6& r0, const Row6& r1, const Row6& r2, int j) {
    float gx = (r0.v[j + 2] - r0.v[j]) + 2.f * (r1.v[j + 2] - r1.v[j]) + (r2.v[j + 2] - r2.v[j]);
    float gy = (r0.v[j] - r2.v[j]) + 2.f * (r0.v[j + 1] - r2.v[j + 1]) + (r0.v[j + 2] - r2.v[j + 2]);
    return fabsf(gx) + fabsf(gy);
}

__global__ __launch_bounds__(TPB, 8) void sobel_loss_main(
    const float* __restrict__ vis, const float* __restrict__ ir,
    const float* __restrict__ X, const float* __restrict__ Y,
    float* __restrict__ part)   // part: [3][NBLOCKS]
{
    __shared__ float red[3][4];

    const int tid  = threadIdx.x;
    const int lane = tid & 63;
    const int wv   = tid >> 6;
    const int x0   = blockIdx.x * XSPAN + lane * 4;
    const int y    = blockIdx.y * 4 + wv;           // this wave's output row
    const size_t base = (size_t)blockIdx.z * (IMG_H * IMG_W);
    const int bid = (blockIdx.z * NBY + blockIdx.y) * NBX + blockIdx.x;

    float j0, j1, j2, j3;            // joint = max(sobel(vis), sobel(ir))
    float sX2 = 0.f, sY2 = 0.f, sL1 = 0.f;

    {   // vis
        Row6 r0 = lrow(vis + base, y - 1, x0, lane);
        Row6 r1 = lrow(vis + base, y,     x0, lane);
        Row6 r2 = lrow(vis + base, y + 1, x0, lane);
        j0 = sob(r0, r1, r2, 0); j1 = sob(r0, r1, r2, 1);
        j2 = sob(r0, r1, r2, 2); j3 = sob(r0, r1, r2, 3);
    }
    __builtin_amdgcn_sched_barrier(0);
    {   // ir
        Row6 r0 = lrow(ir + base, y - 1, x0, lane);
        Row6 r1 = lrow(ir + base, y,     x0, lane);
        Row6 r2 = lrow(ir + base, y + 1, x0, lane);
        j0 = fmaxf(j0, sob(r0, r1, r2, 0)); j1 = fmaxf(j1, sob(r0, r1, r2, 1));
        j2 = fmaxf(j2, sob(r0, r1, r2, 2)); j3 = fmaxf(j3, sob(r0, r1, r2, 3));
    }
    __builtin_amdgcn_sched_barrier(0);
    {   // X
        Row6 r0 = lrow(X + base, y - 1, x0, lane);
        Row6 r1 = lrow(X + base, y,     x0, lane);
        Row6 r2 = lrow(X + base, y + 1, x0, lane);
        float g0 = sob(r0, r1, r2, 0), g1 = sob(r0, r1, r2, 1);
        float g2 = sob(r0, r1, r2, 2), g3 = sob(r0, r1, r2, 3);
        sX2 = g0 * g0 + g1 * g1 + g2 * g2 + g3 * g3;
        sL1 = fabsf(g0 - j0) + fabsf(g1 - j1) + fabsf(g2 - j2) + fabsf(g3 - j3);
    }
    __builtin_amdgcn_sched_barrier(0);
    {   // Y
        Row6 r0 = lrow(Y + base, y - 1, x0, lane);
        Row6 r1 = lrow(Y + base, y,     x0, lane);
        Row6 r2 = lrow(Y + base, y + 1, x0, lane);
        float g0 = sob(r0, r1, r2, 0), g1 = sob(r0, r1, r2, 1);
        float g2 = sob(r0, r1, r2, 2), g3 = sob(r0, r1, r2, 3);
        sY2 = g0 * g0 + g1 * g1 + g2 * g2 + g3 * g3;
    }

    // wave reduce, then 4-wave LDS reduce
    #pragma unroll
    for (int off = 32; off > 0; off >>= 1) {
        sX2 += __shfl_down(sX2, off);
        sY2 += __shfl_down(sY2, off);
        sL1 += __shfl_down(sL1, off);
    }
    if (lane == 0) { red[0][wv] = sX2; red[1][wv] = sY2; red[2][wv] = sL1; }
    __syncthreads();
    if (tid == 0) {
        part[0 * NBLOCKS + bid] = red[0][0] + red[0][1] + red[0][2] + red[0][3];
        part[1 * NBLOCKS + bid] = red[1][0] + red[1][1] + red[1][2] + red[1][3];
        part[2 * NBLOCKS + bid] = red[2][0] + red[2][1] + red[2][2] + red[2][3];
    }
}

__global__ __launch_bounds__(1024) void reduce_finalize(
    const float* __restrict__ part, float* __restrict__ out)
{
    __shared__ float red[3][16];
    const int tid = threadIdx.x;

    float a = 0.f, b = 0.f, c = 0.f;
    for (int i = tid; i < NBLOCKS; i += 1024) {
        a += part[0 * NBLOCKS + i];
        b += part[1 * NBLOCKS + i];
        c += part[2 * NBLOCKS + i];
    }
    #pragma unroll
    for (int off = 32; off > 0; off >>= 1) {
        a += __shfl_down(a, off);
        b += __shfl_down(b, off);
        c += __shfl_down(c, off);
    }
    const int wave = tid >> 6;
    const int lane = tid & 63;
    if (lane == 0) { red[0][wave] = a; red[1][wave] = b; red[2][wave] = c; }
    __syncthreads();
    if (tid == 0) {
        float sa = 0.f, sb = 0.f, sc = 0.f;
        #pragma unroll
        for (int w = 0; w < 16; ++w) { sa += red[0][w]; sb += red[1][w]; sc += red[2][w]; }
        out[0] = sb / sa;                      // loss_in = sumY2 / sumX2
        out[1] = sc * (1.f / (float)NPIX);     // loss_grad = sumL1 / N
    }
}

extern "C" void kernel_launch(void* const* d_in, const int* in_sizes, int n_in,
                              void* d_out, int out_size, void* d_ws, size_t ws_size,
                              hipStream_t stream) {
    const float* vis = (const float*)d_in[0];
    const float* ir  = (const float*)d_in[1];
    const float* X   = (const float*)d_in[2];
    const float* Y   = (const float*)d_in[3];
    float* out = (float*)d_out;
    float* part = (float*)d_ws;   // 3 * NBLOCKS floats = 110 KB

    dim3 grid(NBX, NBY, BATCH);   // 3 x 192 x 16 = 9216 blocks
    sobel_loss_main<<<grid, TPB, 0, stream>>>(vis, ir, X, Y, part);
    reduce_finalize<<<1, 1024, 0, stream>>>(part, out);
}

// Round 8
// 61.896 us; speedup vs baseline: 1.9280x; 1.9280x over previous
//
#include <hip/hip_runtime.h>
#include <math.h>

#define IMG_H 768
#define IMG_W 768
#define BATCH 16
#define TPB 256                     // 4 waves; each wave = one output row, 256-px x-span
#define XSPAN 256
#define NBX (IMG_W / XSPAN)         // 3
#define NBY (IMG_H / 4)             // 192 (4 output rows per block)
#define NBLOCKS (NBX * NBY * BATCH) // 9216
#define NPIX ((size_t)BATCH * IMG_H * IMG_W)  // 9437184

struct Row6 { float v[6]; };        // x0-1 .. x0+4

// Load one image row segment: one float4 + shfl x-halo + 2-lane edge load.
__device__ __forceinline__ Row6 lrow(const float* __restrict__ img, int row, int x0, int lane) {
    Row6 r;
    if (row < 0 || row >= IMG_H) {            // wave-uniform branch
        #pragma unroll
        for (int i = 0; i < 6; ++i) r.v[i] = 0.f;
        return r;
    }
    const float* p = img + row * IMG_W + x0;
    float4 m = *(const float4*)p;             // 16B-aligned
    float ev = 0.f;
    bool e0  = (lane == 0)  & (x0 > 0);
    bool e63 = (lane == 63) & (x0 + 4 < IMG_W);
    if (e0 | e63) ev = p[e0 ? -1 : 4];        // one VMEM, 2 active lanes/wave
    float left  = __shfl_up(m.w, 1);
    float right = __shfl_down(m.x, 1);
    if (lane == 0)  left  = ev;
    if (lane == 63) right = ev;
    r.v[0] = left; r.v[1] = m.x; r.v[2] = m.y; r.v[3] = m.z; r.v[4] = m.w; r.v[5] = right;
    return r;
}

__device__ __forceinline__ float sob(const Row6& r0, const Row6& r1, const Row6& r2, int j) {
    float gx = (r0.v[j + 2] - r0.v[j]) + 2.f * (r1.v[j + 2] - r1.v[j]) + (r2.v[j + 2] - r2.v[j]);
    float gy = (r0.v[j] - r2.v[j]) + 2.f * (r0.v[j + 1] - r2.v[j + 1]) + (r0.v[j + 2] - r2.v[j + 2]);
    return fabsf(gx) + fabsf(gy);
}

__global__ __launch_bounds__(TPB) void sobel_loss_main(
    const float* __restrict__ vis, const float* __restrict__ ir,
    const float* __restrict__ X, const float* __restrict__ Y,
    float* __restrict__ part)   // part: [3][NBLOCKS]
{
    __shared__ float red[3][4];

    const int tid  = threadIdx.x;
    const int lane = tid & 63;
    const int wv   = tid >> 6;
    const int x0   = blockIdx.x * XSPAN + lane * 4;
    const int y    = blockIdx.y * 4 + wv;           // this wave's output row
    const size_t base = (size_t)blockIdx.z * (IMG_H * IMG_W);
    const int bid = (blockIdx.z * NBY + blockIdx.y) * NBX + blockIdx.x;

    float j0, j1, j2, j3;            // joint = max(sobel(vis), sobel(ir))
    float sX2 = 0.f, sY2 = 0.f, sL1 = 0.f;

    {   // vis
        Row6 r0 = lrow(vis + base, y - 1, x0, lane);
        Row6 r1 = lrow(vis + base, y,     x0, lane);
        Row6 r2 = lrow(vis + base, y + 1, x0, lane);
        j0 = sob(r0, r1, r2, 0); j1 = sob(r0, r1, r2, 1);
        j2 = sob(r0, r1, r2, 2); j3 = sob(r0, r1, r2, 3);
    }
    {   // ir
        Row6 r0 = lrow(ir + base, y - 1, x0, lane);
        Row6 r1 = lrow(ir + base, y,     x0, lane);
        Row6 r2 = lrow(ir + base, y + 1, x0, lane);
        j0 = fmaxf(j0, sob(r0, r1, r2, 0)); j1 = fmaxf(j1, sob(r0, r1, r2, 1));
        j2 = fmaxf(j2, sob(r0, r1, r2, 2)); j3 = fmaxf(j3, sob(r0, r1, r2, 3));
    }
    {   // X
        Row6 r0 = lrow(X + base, y - 1, x0, lane);
        Row6 r1 = lrow(X + base, y,     x0, lane);
        Row6 r2 = lrow(X + base, y + 1, x0, lane);
        float g0 = sob(r0, r1, r2, 0), g1 = sob(r0, r1, r2, 1);
        float g2 = sob(r0, r1, r2, 2), g3 = sob(r0, r1, r2, 3);
        sX2 = g0 * g0 + g1 * g1 + g2 * g2 + g3 * g3;
        sL1 = fabsf(g0 - j0) + fabsf(g1 - j1) + fabsf(g2 - j2) + fabsf(g3 - j3);
    }
    {   // Y
        Row6 r0 = lrow(Y + base, y - 1, x0, lane);
        Row6 r1 = lrow(Y + base, y,     x0, lane);
        Row6 r2 = lrow(Y + base, y + 1, x0, lane);
        float g0 = sob(r0, r1, r2, 0), g1 = sob(r0, r1, r2, 1);
        float g2 = sob(r0, r1, r2, 2), g3 = sob(r0, r1, r2, 3);
        sY2 = g0 * g0 + g1 * g1 + g2 * g2 + g3 * g3;
    }

    // wave reduce, then 4-wave LDS reduce
    #pragma unroll
    for (int off = 32; off > 0; off >>= 1) {
        sX2 += __shfl_down(sX2, off);
        sY2 += __shfl_down(sY2, off);
        sL1 += __shfl_down(sL1, off);
    }
    if (lane == 0) { red[0][wv] = sX2; red[1][wv] = sY2; red[2][wv] = sL1; }
    __syncthreads();
    if (tid == 0) {
        part[0 * NBLOCKS + bid] = red[0][0] + red[0][1] + red[0][2] + red[0][3];
        part[1 * NBLOCKS + bid] = red[1][0] + red[1][1] + red[1][2] + red[1][3];
        part[2 * NBLOCKS + bid] = red[2][0] + red[2][1] + red[2][2] + red[2][3];
    }
}

__global__ __launch_bounds__(1024) void reduce_finalize(
    const float* __restrict__ part, float* __restrict__ out)
{
    __shared__ float red[3][16];
    const int tid = threadIdx.x;

    float a = 0.f, b = 0.f, c = 0.f;
    for (int i = tid; i < NBLOCKS; i += 1024) {
        a += part[0 * NBLOCKS + i];
        b += part[1 * NBLOCKS + i];
        c += part[2 * NBLOCKS + i];
    }
    #pragma unroll
    for (int off = 32; off > 0; off >>= 1) {
        a += __shfl_down(a, off);
        b += __shfl_down(b, off);
        c += __shfl_down(c, off);
    }
    const int wave = tid >> 6;
    const int lane = tid & 63;
    if (lane == 0) { red[0][wave] = a; red[1][wave] = b; red[2][wave] = c; }
    __syncthreads();
    if (tid == 0) {
        float sa = 0.f, sb = 0.f, sc = 0.f;
        #pragma unroll
        for (int w = 0; w < 16; ++w) { sa += red[0][w]; sb += red[1][w]; sc += red[2][w]; }
        out[0] = sb / sa;                      // loss_in = sumY2 / sumX2
        out[1] = sc * (1.f / (float)NPIX);     // loss_grad = sumL1 / N
    }
}

extern "C" void kernel_launch(void* const* d_in, const int* in_sizes, int n_in,
                              void* d_out, int out_size, void* d_ws, size_t ws_size,
                              hipStream_t stream) {
    const float* vis = (const float*)d_in[0];
    const float* ir  = (const float*)d_in[1];
    const float* X   = (const float*)d_in[2];
    const float* Y   = (const float*)d_in[3];
    float* out = (float*)d_out;
    float* part = (float*)d_ws;   // 3 * NBLOCKS floats = 110 KB

    dim3 grid(NBX, NBY, BATCH);   // 3 x 192 x 16 = 9216 blocks
    sobel_loss_main<<<grid, TPB, 0, stream>>>(vis, ir, X, Y, part);
    reduce_finalize<<<1, 1024, 0, stream>>>(part, out);
}

// Round 9
// 47.153 us; speedup vs baseline: 2.5308x; 1.3127x over previous
//
#include <hip/hip_runtime.h>
#include <math.h>

#define IMG_H 768
#define IMG_W 768
#define BATCH 16
#define TPB 256                     // 4 waves; each wave = one output row, 256-px x-span
#define XSPAN 256
#define NBX (IMG_W / XSPAN)         // 3
#define NBY (IMG_H / 4)             // 192 (4 output rows per block)
#define NBLOCKS (NBX * NBY * BATCH) // 9216
#define NPIX ((size_t)BATCH * IMG_H * IMG_W)  // 9437184

__global__ __launch_bounds__(TPB) void sobel_loss_main(
    const float* __restrict__ vis, const float* __restrict__ ir,
    const float* __restrict__ X, const float* __restrict__ Y,
    float* __restrict__ part)   // part: [3][NBLOCKS]
{
    __shared__ float red[3][4];

    const int tid  = threadIdx.x;
    const int lane = tid & 63;
    const int wv   = tid >> 6;
    const int x0   = blockIdx.x * XSPAN + lane * 4;
    const int y    = blockIdx.y * 4 + wv;           // this wave's output row
    const size_t base = (size_t)blockIdx.z * (IMG_H * IMG_W);
    const int bid = (blockIdx.z * NBY + blockIdx.y) * NBX + blockIdx.x;

    const float* img[4] = { vis + base, ir + base, X + base, Y + base };

    const bool e0  = (lane == 0)  && (x0 > 0);
    const bool e63 = (lane == 63) && (x0 + 4 < IMG_W);
    const int  eoff = e0 ? -1 : 4;

    // ---------- phase A: issue ALL loads (clamped row => always-legal address,
    // straight-line code, 24 VMEM in flight) ----------
    float4 m[4][3];     // static indices only (full unroll)
    float  ev[4][3];
    #pragma unroll
    for (int im = 0; im < 4; ++im) {
        #pragma unroll
        for (int dy = 0; dy < 3; ++dy) {
            int row = y + dy - 1;
            int rc  = row < 0 ? 0 : (row > IMG_H - 1 ? IMG_H - 1 : row);
            m[im][dy] = *(const float4*)(img[im] + rc * IMG_W + x0);
        }
    }
    #pragma unroll
    for (int im = 0; im < 4; ++im) {
        #pragma unroll
        for (int dy = 0; dy < 3; ++dy) {
            int row = y + dy - 1;
            int rc  = row < 0 ? 0 : (row > IMG_H - 1 ? IMG_H - 1 : row);
            float e = 0.f;
            if (e0 | e63) e = (img[im] + rc * IMG_W + x0)[eoff];  // 2 active lanes
            ev[im][dy] = e;
        }
    }
    __builtin_amdgcn_sched_barrier(0);   // pin: all loads above, all compute below

    // ---------- phase B: mask OOB rows, shfl x-halo, sobel, combine ----------
    float g[4][4];
    #pragma unroll
    for (int im = 0; im < 4; ++im) {
        float r[3][6];
        #pragma unroll
        for (int dy = 0; dy < 3; ++dy) {
            float msk;
            if (dy == 1) msk = 1.f;                     // row = y, always in-bounds
            else {
                int row = y + dy - 1;
                msk = (row >= 0 && row < IMG_H) ? 1.f : 0.f;
            }
            float4 mm = m[im][dy];
            float  e  = ev[im][dy];
            float left  = __shfl_up(mm.w, 1);
            float right = __shfl_down(mm.x, 1);
            if (lane == 0)  left  = e;
            if (lane == 63) right = e;
            r[dy][0] = left  * msk;
            r[dy][1] = mm.x * msk;
            r[dy][2] = mm.y * msk;
            r[dy][3] = mm.z * msk;
            r[dy][4] = mm.w * msk;
            r[dy][5] = right * msk;
        }
        #pragma unroll
        for (int jj = 0; jj < 4; ++jj) {
            float gx = (r[0][jj + 2] - r[0][jj]) + 2.f * (r[1][jj + 2] - r[1][jj]) + (r[2][jj + 2] - r[2][jj]);
            float gy = (r[0][jj] - r[2][jj]) + 2.f * (r[0][jj + 1] - r[2][jj + 1]) + (r[0][jj + 2] - r[2][jj + 2]);
            g[im][jj] = fabsf(gx) + fabsf(gy);
        }
    }

    float sX2 = 0.f, sY2 = 0.f, sL1 = 0.f;
    #pragma unroll
    for (int jj = 0; jj < 4; ++jj) {
        float jnt = fmaxf(g[0][jj], g[1][jj]);
        float gX = g[2][jj], gY = g[3][jj];
        sX2 += gX * gX;
        sY2 += gY * gY;
        sL1 += fabsf(gX - jnt);
    }

    // wave reduce, then 4-wave LDS reduce
    #pragma unroll
    for (int off = 32; off > 0; off >>= 1) {
        sX2 += __shfl_down(sX2, off);
        sY2 += __shfl_down(sY2, off);
        sL1 += __shfl_down(sL1, off);
    }
    if (lane == 0) { red[0][wv] = sX2; red[1][wv] = sY2; red[2][wv] = sL1; }
    __syncthreads();
    if (tid == 0) {
        part[0 * NBLOCKS + bid] = red[0][0] + red[0][1] + red[0][2] + red[0][3];
        part[1 * NBLOCKS + bid] = red[1][0] + red[1][1] + red[1][2] + red[1][3];
        part[2 * NBLOCKS + bid] = red[2][0] + red[2][1] + red[2][2] + red[2][3];
    }
}

__global__ __launch_bounds__(1024) void reduce_finalize(
    const float* __restrict__ part, float* __restrict__ out)
{
    __shared__ float red[3][16];
    const int tid = threadIdx.x;

    float a = 0.f, b = 0.f, c = 0.f;
    for (int i = tid; i < NBLOCKS; i += 1024) {
        a += part[0 * NBLOCKS + i];
        b += part[1 * NBLOCKS + i];
        c += part[2 * NBLOCKS + i];
    }
    #pragma unroll
    for (int off = 32; off > 0; off >>= 1) {
        a += __shfl_down(a, off);
        b += __shfl_down(b, off);
        c += __shfl_down(c, off);
    }
    const int wave = tid >> 6;
    const int lane = tid & 63;
    if (lane == 0) { red[0][wave] = a; red[1][wave] = b; red[2][wave] = c; }
    __syncthreads();
    if (tid == 0) {
        float sa = 0.f, sb = 0.f, sc = 0.f;
        #pragma unroll
        for (int w = 0; w < 16; ++w) { sa += red[0][w]; sb += red[1][w]; sc += red[2][w]; }
        out[0] = sb / sa;                      // loss_in = sumY2 / sumX2
        out[1] = sc * (1.f / (float)NPIX);     // loss_grad = sumL1 / N
    }
}

extern "C" void kernel_launch(void* const* d_in, const int* in_sizes, int n_in,
                              void* d_out, int out_size, void* d_ws, size_t ws_size,
                              hipStream_t stream) {
    const float* vis = (const float*)d_in[0];
    const float* ir  = (const float*)d_in[1];
    const float* X   = (const float*)d_in[2];
    const float* Y   = (const float*)d_in[3];
    float* out = (float*)d_out;
    float* part = (float*)d_ws;   // 3 * NBLOCKS floats = 110 KB

    dim3 grid(NBX, NBY, BATCH);   // 3 x 192 x 16 = 9216 blocks
    sobel_loss_main<<<grid, TPB, 0, stream>>>(vis, ir, X, Y, part);
    reduce_finalize<<<1, 1024, 0, stream>>>(part, out);
}

// Round 10
// 41.483 us; speedup vs baseline: 2.8767x; 1.1367x over previous
//
#include <hip/hip_runtime.h>
#include <math.h>

#define IMG_H 768
#define IMG_W 768
#define BATCH 16
#define TH 4                        // output rows per block (full 768-px width)
#define TPB 256                     // 4 waves; wave w computes output row y0+w
#define NSTRIPS (IMG_H / TH)        // 192
#define NBLOCKS (NSTRIPS * BATCH)   // 3072
#define NPIX ((size_t)BATCH * IMG_H * IMG_W)  // 9437184

typedef const __attribute__((address_space(1))) float* gp1_t;
typedef __attribute__((address_space(3))) float* lp3_t;

__global__ __launch_bounds__(TPB) void sobel_loss_main(
    const float* __restrict__ vis, const float* __restrict__ ir,
    const float* __restrict__ X, const float* __restrict__ Y,
    float* __restrict__ part)   // part: [3][NBLOCKS]
{
    __shared__ __align__(16) float lds[4][TH + 2][IMG_W];   // 73728 B
    __shared__ float red[3][4];

    const int tid  = threadIdx.x;
    const int lane = tid & 63;
    const int wv   = tid >> 6;
    const int y0   = blockIdx.x * TH;
    const size_t base = (size_t)blockIdx.y * (IMG_H * IMG_W);
    const int bid = blockIdx.y * NSTRIPS + blockIdx.x;

    const float* img[4] = { vis + base, ir + base, X + base, Y + base };

    // ---- stage: wave wv DMAs image wv's 6 rows x 3 segs = 18 x 1KB chunks.
    // global_load_lds: no VGPR payload, all 72 chunks in flight at once.
    {
        const float* ip = img[wv];
        #pragma unroll
        for (int i = 0; i < 3 * (TH + 2); ++i) {
            const int row = i / 3, seg = i % 3;
            int gr = y0 - 1 + row;
            int rc = gr < 0 ? 0 : (gr > IMG_H - 1 ? IMG_H - 1 : gr);   // clamp; OOB zeroed below
            const float* src = ip + (size_t)rc * IMG_W + seg * 256 + lane * 4;
            __builtin_amdgcn_global_load_lds((gp1_t)src, (lp3_t)&lds[wv][row][seg * 256], 16, 0, 0);
        }
    }
    __syncthreads();   // compiler drains vmcnt(0) before s_barrier -> DMA complete

    // zero OOB halo rows (only first/last strip; block-uniform branch)
    if (y0 == 0) {
        for (int i = tid; i < IMG_W; i += TPB) {
            lds[0][0][i] = 0.f; lds[1][0][i] = 0.f; lds[2][0][i] = 0.f; lds[3][0][i] = 0.f;
        }
        __syncthreads();
    } else if (y0 + TH == IMG_H) {
        for (int i = tid; i < IMG_W; i += TPB) {
            lds[0][TH + 1][i] = 0.f; lds[1][TH + 1][i] = 0.f; lds[2][TH + 1][i] = 0.f; lds[3][TH + 1][i] = 0.f;
        }
        __syncthreads();
    }

    // ---- compute: wave wv -> output row y0+wv; lane -> 12 px [lane*12, lane*12+12) ----
    const int r0 = wv, r1 = wv + 1, r2 = wv + 2;
    const int xb = lane * 12;       // 48B offset: 16B-aligned

    float jnt[12];
    float sX2 = 0.f, sY2 = 0.f, sL1 = 0.f;

    #pragma unroll
    for (int im = 0; im < 4; ++im) {
        float4 t0 = *(const float4*)&lds[im][r0][xb];
        float4 t1 = *(const float4*)&lds[im][r0][xb + 4];
        float4 t2 = *(const float4*)&lds[im][r0][xb + 8];
        float4 m0 = *(const float4*)&lds[im][r1][xb];
        float4 m1 = *(const float4*)&lds[im][r1][xb + 4];
        float4 m2 = *(const float4*)&lds[im][r1][xb + 8];
        float4 b0 = *(const float4*)&lds[im][r2][xb];
        float4 b1 = *(const float4*)&lds[im][r2][xb + 4];
        float4 b2 = *(const float4*)&lds[im][r2][xb + 8];

        float T[14], M[14], B[14];
        T[1] = t0.x; T[2] = t0.y; T[3] = t0.z; T[4] = t0.w;
        T[5] = t1.x; T[6] = t1.y; T[7] = t1.z; T[8] = t1.w;
        T[9] = t2.x; T[10] = t2.y; T[11] = t2.z; T[12] = t2.w;
        M[1] = m0.x; M[2] = m0.y; M[3] = m0.z; M[4] = m0.w;
        M[5] = m1.x; M[6] = m1.y; M[7] = m1.z; M[8] = m1.w;
        M[9] = m2.x; M[10] = m2.y; M[11] = m2.z; M[12] = m2.w;
        B[1] = b0.x; B[2] = b0.y; B[3] = b0.z; B[4] = b0.w;
        B[5] = b1.x; B[6] = b1.y; B[7] = b1.z; B[8] = b1.w;
        B[9] = b2.x; B[10] = b2.y; B[11] = b2.z; B[12] = b2.w;

        float tl = __shfl_up(t2.w, 1),  tr = __shfl_down(t0.x, 1);
        float ml = __shfl_up(m2.w, 1),  mr = __shfl_down(m0.x, 1);
        float bl = __shfl_up(b2.w, 1),  br = __shfl_down(b0.x, 1);
        T[0] = (lane == 0) ? 0.f : tl;  T[13] = (lane == 63) ? 0.f : tr;
        M[0] = (lane == 0) ? 0.f : ml;  M[13] = (lane == 63) ? 0.f : mr;
        B[0] = (lane == 0) ? 0.f : bl;  B[13] = (lane == 63) ? 0.f : br;

        float s[14], d[14];
        #pragma unroll
        for (int j = 0; j < 14; ++j) { s[j] = T[j] + B[j]; d[j] = T[j] - B[j]; }

        float g[12];
        #pragma unroll
        for (int j = 0; j < 12; ++j) {
            float gx = (s[j + 2] - s[j]) + 2.f * (M[j + 2] - M[j]);
            float gy = d[j] + 2.f * d[j + 1] + d[j + 2];
            g[j] = fabsf(gx) + fabsf(gy);
        }

        if (im == 0) {
            #pragma unroll
            for (int j = 0; j < 12; ++j) jnt[j] = g[j];
        } else if (im == 1) {
            #pragma unroll
            for (int j = 0; j < 12; ++j) jnt[j] = fmaxf(jnt[j], g[j]);
        } else if (im == 2) {
            #pragma unroll
            for (int j = 0; j < 12; ++j) {
                sX2 += g[j] * g[j];
                sL1 += fabsf(g[j] - jnt[j]);
            }
        } else {
            #pragma unroll
            for (int j = 0; j < 12; ++j) sY2 += g[j] * g[j];
        }
    }

    // wave reduce, then 4-wave LDS reduce
    #pragma unroll
    for (int off = 32; off > 0; off >>= 1) {
        sX2 += __shfl_down(sX2, off);
        sY2 += __shfl_down(sY2, off);
        sL1 += __shfl_down(sL1, off);
    }
    if (lane == 0) { red[0][wv] = sX2; red[1][wv] = sY2; red[2][wv] = sL1; }
    __syncthreads();
    if (tid == 0) {
        part[0 * NBLOCKS + bid] = red[0][0] + red[0][1] + red[0][2] + red[0][3];
        part[1 * NBLOCKS + bid] = red[1][0] + red[1][1] + red[1][2] + red[1][3];
        part[2 * NBLOCKS + bid] = red[2][0] + red[2][1] + red[2][2] + red[2][3];
    }
}

__global__ __launch_bounds__(1024) void reduce_finalize(
    const float* __restrict__ part, float* __restrict__ out)
{
    __shared__ float red[3][16];
    const int tid = threadIdx.x;

    float a = 0.f, b = 0.f, c = 0.f;
    for (int i = tid; i < NBLOCKS; i += 1024) {
        a += part[0 * NBLOCKS + i];
        b += part[1 * NBLOCKS + i];
        c += part[2 * NBLOCKS + i];
    }
    #pragma unroll
    for (int off = 32; off > 0; off >>= 1) {
        a += __shfl_down(a, off);
        b += __shfl_down(b, off);
        c += __shfl_down(c, off);
    }
    const int wave = tid >> 6;
    const int lane = tid & 63;
    if (lane == 0) { red[0][wave] = a; red[1][wave] = b; red[2][wave] = c; }
    __syncthreads();
    if (tid == 0) {
        float sa = 0.f, sb = 0.f, sc = 0.f;
        #pragma unroll
        for (int w = 0; w < 16; ++w) { sa += red[0][w]; sb += red[1][w]; sc += red[2][w]; }
        out[0] = sb / sa;                      // loss_in = sumY2 / sumX2
        out[1] = sc * (1.f / (float)NPIX);     // loss_grad = sumL1 / N
    }
}

extern "C" void kernel_launch(void* const* d_in, const int* in_sizes, int n_in,
                              void* d_out, int out_size, void* d_ws, size_t ws_size,
                              hipStream_t stream) {
    const float* vis = (const float*)d_in[0];
    const float* ir  = (const float*)d_in[1];
    const float* X   = (const float*)d_in[2];
    const float* Y   = (const float*)d_in[3];
    float* out = (float*)d_out;
    float* part = (float*)d_ws;   // 3 * NBLOCKS floats = 36 KB

    dim3 grid(NSTRIPS, BATCH);    // 192 x 16 = 3072 blocks
    sobel_loss_main<<<grid, TPB, 0, stream>>>(vis, ir, X, Y, part);
    reduce_finalize<<<1, 1024, 0, stream>>>(part, out);
}